// Round 9
// baseline (329.824 us; speedup 1.0000x reference)
//
#include <hip/hip_runtime.h>
#include <math.h>

#define TPB 256
#define TPBA 448
#define TPBC 512

// padded strides chosen so window-read lane banks = (4*py + 2*px) % 32 -> worst 2-way (free)
#define XS_S   34          // xs_p row stride (A)
#define SM1_S  26          // smap1 row stride (A)
#define SM1_C  624         // smap1 channel stride = 24*26
#define H1P_R  18          // h1p row stride (B)
#define H1P_C  252         // h1p channel stride = 14*18
#define H1P_I  1512        // h1p image stride = 6*252

typedef float v2f __attribute__((ext_vector_type(2)));

// acc(lo,hi) += broadcast(ap.lo) * w(lo,hi)
__device__ __forceinline__ void pk_lo(v2f& acc, v2f ap, v2f w) {
    asm("v_pk_fma_f32 %0, %1, %2, %0 op_sel:[0,0,0] op_sel_hi:[0,1,1]"
        : "+v"(acc) : "v"(ap), "v"(w));
}
// acc(lo,hi) += broadcast(ap.hi) * w(lo,hi)
__device__ __forceinline__ void pk_hi(v2f& acc, v2f ap, v2f w) {
    asm("v_pk_fma_f32 %0, %1, %2, %0 op_sel:[1,0,0] op_sel_hi:[1,1,1]"
        : "+v"(acc) : "v"(ap), "v"(w));
}

// ---------------- workspace layout (floats) ----------------
#define OFF_WA_SX 0
#define OFF_WA_YY 300
#define OFF_WB_SX 464
#define OFF_WB_YY 5264
#define OFF_WF1T  7664
#define OFF_WF2T  55664
#define OFF_WF3T  65744
#define OFF_H1    66592
#define OFF_H2    7144480
#define WS_FLOATS 10421280ull
#define REQ_WS_BYTES (WS_FLOATS * 4ull)

// bilinear sample with zeros padding; logical NxN map stored with row stride S
__device__ __forceinline__ float bilin_zero_s(const float* __restrict__ img, int N, int S,
                                              float gx, float gy) {
    float fx = (gx + 1.0f) * (0.5f * (float)N) - 0.5f;
    float fy = (gy + 1.0f) * (0.5f * (float)N) - 0.5f;
    float x0 = floorf(fx), y0 = floorf(fy);
    float wx1 = fx - x0, wy1 = fy - y0;
    float wx0 = 1.0f - wx1, wy0 = 1.0f - wy1;
    float x1 = x0 + 1.0f, y1 = y0 + 1.0f;
    float Nm1 = (float)(N - 1);
    int xi0 = (int)fminf(fmaxf(x0, 0.0f), Nm1);
    int yi0 = (int)fminf(fmaxf(y0, 0.0f), Nm1);
    int xi1 = (int)fminf(fmaxf(x1, 0.0f), Nm1);
    int yi1 = (int)fminf(fmaxf(y1, 0.0f), Nm1);
    bool vx0 = (x0 >= 0.0f) && (x0 < (float)N);
    bool vx1 = (x1 >= 0.0f) && (x1 < (float)N);
    bool vy0 = (y0 >= 0.0f) && (y0 < (float)N);
    bool vy1 = (y1 >= 0.0f) && (y1 < (float)N);
    float v00 = (vy0 && vx0) ? img[yi0 * S + xi0] : 0.0f;
    float v01 = (vy0 && vx1) ? img[yi0 * S + xi1] : 0.0f;
    float v10 = (vy1 && vx0) ? img[yi1 * S + xi0] : 0.0f;
    float v11 = (vy1 && vx1) ? img[yi1 * S + xi1] : 0.0f;
    return v00 * wy0 * wx0 + v01 * wy0 * wx1 + v10 * wy1 * wx0 + v11 * wy1 * wx1;
}

// ================= prep: pack conv weights, transpose FC weights =================
__global__ __launch_bounds__(TPB) void lenet_prep(
    const float* __restrict__ w1s, const float* __restrict__ w1x, const float* __restrict__ w1y,
    const float* __restrict__ w2s, const float* __restrict__ w2x, const float* __restrict__ w2y,
    const float* __restrict__ wf1, const float* __restrict__ wf2, const float* __restrict__ wf3,
    float* __restrict__ wsf)
{
    int g = blockIdx.x * TPB + threadIdx.x;
    int stride = gridDim.x * TPB;
    for (int i = g; i < 75; i += stride) {
        int cp = i / 25, t = i % 25;
        int cA = (2 * cp) * 25 + t, cB = (2 * cp + 1) * 25 + t;
        float* p = wsf + OFF_WA_SX + i * 4;
        p[0] = w1s[cA]; p[1] = w1x[cA]; p[2] = w1s[cB]; p[3] = w1x[cB];
        wsf[OFF_WA_YY + i * 2 + 0] = w1y[cA];
        wsf[OFF_WA_YY + i * 2 + 1] = w1y[cB];
    }
    for (int e = g; e < 1200; e += stride) {
        int cp = e / 150, rem = e % 150;
        int iA = cp * 150 + rem, iB = (cp + 8) * 150 + rem;
        float* pp = wsf + OFF_WB_SX + e * 4;
        pp[0] = w2s[iA]; pp[1] = w2s[iB]; pp[2] = w2x[iA]; pp[3] = w2x[iB];
        wsf[OFF_WB_YY + e * 2 + 0] = w2y[iA];
        wsf[OFF_WB_YY + e * 2 + 1] = w2y[iB];
    }
    for (int i = g; i < 48000; i += stride) { int k = i / 120, o = i % 120; wsf[OFF_WF1T + i] = wf1[o * 400 + k]; }
    for (int i = g; i < 10080; i += stride) { int k = i / 84,  o = i % 84;  wsf[OFF_WF2T + i] = wf2[o * 120 + k]; }
    for (int i = g; i < 840;   i += stride) { int k = i / 10,  o = i % 10;  wsf[OFF_WF3T + i] = wf3[o * 84 + k]; }
}

// ================= kernel A: conv1 + sample + relu + pool -> h1 =================
__global__ __launch_bounds__(TPBA) void lenetA(
    const float* __restrict__ x, const float* __restrict__ wsf,
    const float* __restrict__ b1s, const float* __restrict__ b1x, const float* __restrict__ b1y,
    float* __restrict__ h1)
{
    __shared__ __align__(16) float xs_p[28 * XS_S];   // padded 28 rows, stride 34
    __shared__ float4 w1i[150];
    __shared__ float4 b1w[3];
    __shared__ v2f    b1yw[3];
    __shared__ __align__(16) float smap1[6 * SM1_C];  // [6][24 rows x stride 26]

    const int tid = threadIdx.x, b = blockIdx.x;
    const float* xp = x + b * 676;
    for (int i = tid; i < 28 * XS_S; i += TPBA) {
        int r = i / XS_S, c = i % XS_S;
        float v = 0.0f;
        if (c < 28 && r >= 1 && r <= 26 && c >= 1 && c <= 26) v = xp[(r - 1) * 26 + (c - 1)];
        xs_p[i] = v;
    }
    if (tid < 150) w1i[tid] = ((const float4*)(wsf + OFF_WA_SX))[tid];
    if (tid < 3) {
        b1w[tid]  = make_float4(b1s[2 * tid], b1x[2 * tid], b1s[2 * tid + 1], b1x[2 * tid + 1]);
        b1yw[tid] = (v2f){b1y[2 * tid], b1y[2 * tid + 1]};
    }
    __syncthreads();

    const v2f* wyy = (const v2f*)(wsf + OFF_WA_YY);

    const int cp = tid / 144, p = tid % 144;
    const int py = p / 12, px = p % 12;
    const bool act = (tid < 432);

    float gxa[2][2][2], gya[2][2][2];
    if (act) {
        v2f aw[6][3];
        #pragma unroll
        for (int r = 0; r < 6; ++r) {
            const v2f* rp = (const v2f*)&xs_p[(2 * py + r) * XS_S + 2 * px];
            aw[r][0] = rp[0]; aw[r][1] = rp[1]; aw[r][2] = rp[2];
        }
        int c0 = 2 * cp, c1 = 2 * cp + 1;
        v2f a0[2][2], a1[2][2], ay[2][2];
        {
            float4 bb = b1w[cp];
            v2f i0 = {bb.x, bb.y};
            v2f i1 = {bb.z, bb.w};
            v2f iy = b1yw[cp];
            #pragma unroll
            for (int dy = 0; dy < 2; ++dy)
                #pragma unroll
                for (int dx = 0; dx < 2; ++dx) { a0[dy][dx] = i0; a1[dy][dx] = i1; ay[dy][dx] = iy; }
        }
        const float4* wp  = &w1i[cp * 25];
        const v2f*    wyp = wyy + cp * 25;
        #pragma unroll
        for (int ky = 0; ky < 5; ++ky)
            #pragma unroll
            for (int kx = 0; kx < 5; ++kx) {
                float4 w4 = wp[ky * 5 + kx];
                v2f wA = {w4.x, w4.y};
                v2f wB = {w4.z, w4.w};
                v2f wy = wyp[ky * 5 + kx];
                #pragma unroll
                for (int dy = 0; dy < 2; ++dy)
                    #pragma unroll
                    for (int dx = 0; dx < 2; ++dx) {
                        int cc = kx + dx;
                        v2f ap = aw[ky + dy][cc >> 1];
                        if ((cc & 1) == 0) {
                            pk_lo(a0[dy][dx], ap, wA);
                            pk_lo(a1[dy][dx], ap, wB);
                            pk_lo(ay[dy][dx], ap, wy);
                        } else {
                            pk_hi(a0[dy][dx], ap, wA);
                            pk_hi(a1[dy][dx], ap, wB);
                            pk_hi(ay[dy][dx], ap, wy);
                        }
                    }
            }
        {
            int base0 = (2 * py) * SM1_S + 2 * px;
            int base1 = base0 + SM1_S;
            *(v2f*)&smap1[c0 * SM1_C + base0] = (v2f){a0[0][0].x, a0[0][1].x};
            *(v2f*)&smap1[c0 * SM1_C + base1] = (v2f){a0[1][0].x, a0[1][1].x};
            *(v2f*)&smap1[c1 * SM1_C + base0] = (v2f){a1[0][0].x, a1[0][1].x};
            *(v2f*)&smap1[c1 * SM1_C + base1] = (v2f){a1[1][0].x, a1[1][1].x};
        }
        #pragma unroll
        for (int dy = 0; dy < 2; ++dy)
            #pragma unroll
            for (int dx = 0; dx < 2; ++dx) {
                gxa[0][dy][dx] = a0[dy][dx].y;  gya[0][dy][dx] = ay[dy][dx].x;
                gxa[1][dy][dx] = a1[dy][dx].y;  gya[1][dy][dx] = ay[dy][dx].y;
            }
    }
    __syncthreads();

    if (act) {
        #pragma unroll
        for (int ch = 0; ch < 2; ++ch) {
            int c = 2 * cp + ch;
            const float* smc = &smap1[c * SM1_C];
            float mx = 0.0f;
            #pragma unroll
            for (int dy = 0; dy < 2; ++dy)
                #pragma unroll
                for (int dx = 0; dx < 2; ++dx)
                    mx = fmaxf(mx, bilin_zero_s(smc, 24, SM1_S, gxa[ch][dy][dx], gya[ch][dy][dx]));
            h1[(size_t)b * 864 + c * 144 + p] = mx;
        }
    }
}

// ================= kernel B: wave-synchronous conv2 + sample + relu + pool =================
__global__ __launch_bounds__(TPB, 8) void lenetB(
    const float* __restrict__ h1, const float* __restrict__ wsf,
    const float* __restrict__ b2s, const float* __restrict__ b2x, const float* __restrict__ b2y,
    float* __restrict__ h2)
{
    __shared__ __align__(16) float h1p[2 * H1P_I];      // padded [2][6][14 x stride 18]
    __shared__ __align__(16) float wsm[4][2][2][100];   // [wave][img][ch-slot][10x10]

    const int tid = threadIdx.x, b = blockIdx.x;

    for (int i = tid; i < 2 * H1P_I; i += TPB) {
        int im = i / H1P_I;
        int k = i - im * H1P_I;
        int ch = k / H1P_C, p2 = k % H1P_C;
        int r = p2 / H1P_R, c = p2 % H1P_R;
        float v = 0.0f;
        if (c < 14 && r >= 1 && r <= 12 && c >= 1 && c <= 12)
            v = h1[(size_t)(2 * b + im) * 864 + ch * 144 + (r - 1) * 12 + (c - 1)];
        h1p[i] = v;
    }
    __syncthreads();  // the only block barrier

    const int lane = tid & 63;
    const int wvu  = __builtin_amdgcn_readfirstlane(tid >> 6);
    const int img  = lane >> 5;
    const int p    = lane & 31;
    const bool act = (p < 25);
    const int py = p / 5, px = p % 5;

    const float4* wsx = (const float4*)(wsf + OFF_WB_SX);
    const v2f*    wyy = (const v2f*)   (wsf + OFF_WB_YY);
    float* smw = &wsm[wvu][img][0][0];
    const float* h1pi = &h1p[img * H1P_I];

    #pragma unroll
    for (int rep = 0; rep < 2; ++rep) {
        const int cp = wvu + 4 * rep;
        if (rep) {
            asm volatile("s_waitcnt lgkmcnt(0)" ::: "memory");
            __builtin_amdgcn_sched_barrier(0);
        }
        v2f as[2][2], ax[2][2], ay[2][2];
        if (act) {
            {
                v2f is = {b2s[cp], b2s[cp + 8]};
                v2f ix = {b2x[cp], b2x[cp + 8]};
                v2f iy = {b2y[cp], b2y[cp + 8]};
                #pragma unroll
                for (int dy = 0; dy < 2; ++dy)
                    #pragma unroll
                    for (int dx = 0; dx < 2; ++dx) { as[dy][dx] = is; ax[dy][dx] = ix; ay[dy][dx] = iy; }
            }
            #pragma unroll
            for (int i = 0; i < 6; ++i) {
                v2f aw[6][3];
                #pragma unroll
                for (int r = 0; r < 6; ++r) {
                    const v2f* rp = (const v2f*)&h1pi[i * H1P_C + (2 * py + r) * H1P_R + 2 * px];
                    aw[r][0] = rp[0]; aw[r][1] = rp[1]; aw[r][2] = rp[2];
                }
                const float4* wt  = wsx + (cp * 6 + i) * 25;
                const v2f*    wyt = wyy + (cp * 6 + i) * 25;
                #pragma unroll
                for (int ky = 0; ky < 5; ++ky)
                    #pragma unroll
                    for (int kx = 0; kx < 5; ++kx) {
                        float4 w4 = wt[ky * 5 + kx];
                        v2f ws = {w4.x, w4.y};
                        v2f wx = {w4.z, w4.w};
                        v2f wy = wyt[ky * 5 + kx];
                        #pragma unroll
                        for (int dy = 0; dy < 2; ++dy)
                            #pragma unroll
                            for (int dx = 0; dx < 2; ++dx) {
                                int cc = kx + dx;
                                v2f ap = aw[ky + dy][cc >> 1];
                                if ((cc & 1) == 0) {
                                    pk_lo(as[dy][dx], ap, ws);
                                    pk_lo(ax[dy][dx], ap, wx);
                                    pk_lo(ay[dy][dx], ap, wy);
                                } else {
                                    pk_hi(as[dy][dx], ap, ws);
                                    pk_hi(ax[dy][dx], ap, wx);
                                    pk_hi(ay[dy][dx], ap, wy);
                                }
                            }
                    }
            }
            {
                int base0 = (2 * py) * 10 + 2 * px;
                int base1 = base0 + 10;
                *(v2f*)&smw[base0]       = (v2f){as[0][0].x, as[0][1].x};
                *(v2f*)&smw[base1]       = (v2f){as[1][0].x, as[1][1].x};
                *(v2f*)&smw[100 + base0] = (v2f){as[0][0].y, as[0][1].y};
                *(v2f*)&smw[100 + base1] = (v2f){as[1][0].y, as[1][1].y};
            }
        }
        asm volatile("s_waitcnt lgkmcnt(0)" ::: "memory");
        __builtin_amdgcn_sched_barrier(0);
        if (act) {
            #pragma unroll
            for (int slot = 0; slot < 2; ++slot) {
                int c = cp + slot * 8;
                const float* smc = &smw[slot * 100];
                float mx = 0.0f;
                #pragma unroll
                for (int dy = 0; dy < 2; ++dy)
                    #pragma unroll
                    for (int dx = 0; dx < 2; ++dx) {
                        float gx = slot ? ax[dy][dx].y : ax[dy][dx].x;
                        float gy = slot ? ay[dy][dx].y : ay[dy][dx].x;
                        mx = fmaxf(mx, bilin_zero_s(smc, 10, 10, gx, gy));
                    }
                h2[(size_t)(2 * b + img) * 400 + c * 25 + p] = mx;
            }
        }
    }
}

// ================= kernel C: FC1+FC2+FC3+softmax. 8 waves, 2 images per wave =================
__global__ __launch_bounds__(TPBC) void lenetC(
    const float* __restrict__ h2, const float* __restrict__ wsf,
    const float* __restrict__ bf1, const float* __restrict__ bf2, const float* __restrict__ bf3,
    float* __restrict__ out)
{
    __shared__ __align__(16) float h2s[8][2][400];
    __shared__ float f1s[8][2][120];
    __shared__ float f2s[8][2][84];
    __shared__ float f3s[8][2][10];

    const int tid = threadIdx.x;
    const int w = tid >> 6, lane = tid & 63;
    const int img0 = blockIdx.x * 16 + w * 2;

    for (int j = 0; j < 2; ++j) {
        float4*       dst = (float4*)&h2s[w][j][0];
        const float4* src = (const float4*)&h2[(img0 + j) * 400];
        for (int k = lane; k < 100; k += 64) dst[k] = src[k];
    }
    __syncthreads();

    {
        const float* wf1T = wsf + OFF_WF1T;
        float acc1[2] = {0, 0}, acc2[2] = {0, 0};
        for (int k = 0; k < 400; ++k) {
            float wa = wf1T[k * 120 + lane];
            float wb = (lane < 56) ? wf1T[k * 120 + 64 + lane] : 0.0f;
            #pragma unroll
            for (int j = 0; j < 2; ++j) {
                float hv = h2s[w][j][k];
                acc1[j] = fmaf(hv, wa, acc1[j]);
                acc2[j] = fmaf(hv, wb, acc2[j]);
            }
        }
        float bb1 = bf1[lane];
        float bb2 = (lane < 56) ? bf1[64 + lane] : 0.0f;
        #pragma unroll
        for (int j = 0; j < 2; ++j) {
            f1s[w][j][lane] = fmaxf(acc1[j] + bb1, 0.0f);
            if (lane < 56) f1s[w][j][64 + lane] = fmaxf(acc2[j] + bb2, 0.0f);
        }
    }
    __syncthreads();

    {
        const float* wf2T = wsf + OFF_WF2T;
        float acc1[2], acc2[2];
        float bb1 = bf2[lane];
        float bb2 = (lane < 20) ? bf2[64 + lane] : 0.0f;
        #pragma unroll
        for (int j = 0; j < 2; ++j) { acc1[j] = bb1; acc2[j] = bb2; }
        for (int k = 0; k < 120; ++k) {
            float wa = wf2T[k * 84 + lane];
            float wb = (lane < 20) ? wf2T[k * 84 + 64 + lane] : 0.0f;
            #pragma unroll
            for (int j = 0; j < 2; ++j) {
                float hv = f1s[w][j][k];
                acc1[j] = fmaf(hv, wa, acc1[j]);
                acc2[j] = fmaf(hv, wb, acc2[j]);
            }
        }
        #pragma unroll
        for (int j = 0; j < 2; ++j) {
            f2s[w][j][lane] = fmaxf(acc1[j], 0.0f);
            if (lane < 20) f2s[w][j][64 + lane] = fmaxf(acc2[j], 0.0f);
        }
    }
    __syncthreads();

    if (lane < 10) {
        const float* wf3T = wsf + OFF_WF3T;
        float acc[2];
        float bb = bf3[lane];
        #pragma unroll
        for (int j = 0; j < 2; ++j) acc[j] = bb;
        for (int k = 0; k < 84; ++k) {
            float wv = wf3T[k * 10 + lane];
            #pragma unroll
            for (int j = 0; j < 2; ++j) acc[j] = fmaf(f2s[w][j][k], wv, acc[j]);
        }
        #pragma unroll
        for (int j = 0; j < 2; ++j) f3s[w][j][lane] = acc[j];
    }
    __syncthreads();

    if (lane < 20) {
        int j = lane / 10, c = lane % 10;
        float m = f3s[w][j][0];
        #pragma unroll
        for (int q = 1; q < 10; ++q) m = fmaxf(m, f3s[w][j][q]);
        float ssum = 0.0f;
        #pragma unroll
        for (int q = 0; q < 10; ++q) ssum += expf(f3s[w][j][q] - m);
        out[(img0 + j) * 10 + c] = expf(f3s[w][j][c] - m) / ssum;
    }
}

// ================= fallback: fully-fused kernel (used if ws too small) =================
__global__ __launch_bounds__(TPB, 2) void lenet_off_fused(
    const float* __restrict__ x,
    const float* __restrict__ w1s, const float* __restrict__ b1s,
    const float* __restrict__ w1x, const float* __restrict__ b1x,
    const float* __restrict__ w1y, const float* __restrict__ b1y,
    const float* __restrict__ w2s, const float* __restrict__ b2s,
    const float* __restrict__ w2x, const float* __restrict__ b2x,
    const float* __restrict__ w2y, const float* __restrict__ b2y,
    const float* __restrict__ wf1, const float* __restrict__ bf1,
    const float* __restrict__ wf2, const float* __restrict__ bf2,
    const float* __restrict__ wf3, const float* __restrict__ bf3,
    float* __restrict__ out)
{
    __shared__ __align__(16) float  xs_p[784];
    __shared__ float4 w1i[150];
    __shared__ float4 b1i[6];
    __shared__ float4 w2i[2400];
    __shared__ float4 b2i[16];
    __shared__ __align__(16) float  smap1[3456];
    __shared__ __align__(16) float  h1p[1176];
    __shared__ __align__(16) float  smap2[1600];
    __shared__ __align__(16) float  h2[400];
    __shared__ __align__(16) float  f1[120];
    __shared__ __align__(16) float  f2[84];
    __shared__ float  f3[10];

    const int tid = threadIdx.x;
    const int b   = blockIdx.x;

    const float* xp = x + b * 676;
    for (int i = tid; i < 784; i += TPB) {
        int r = i / 28, c = i % 28;
        float v = 0.0f;
        if (r >= 1 && r <= 26 && c >= 1 && c <= 26) v = xp[(r - 1) * 26 + (c - 1)];
        xs_p[i] = v;
    }
    for (int i = tid; i < 150; i += TPB)
        w1i[i] = make_float4(w1s[i], w1x[i], w1y[i], 0.0f);
    if (tid < 6)  b1i[tid] = make_float4(b1s[tid], b1x[tid], b1y[tid], 0.0f);
    for (int i = tid; i < 2400; i += TPB)
        w2i[i] = make_float4(w2s[i], w2x[i], w2y[i], 0.0f);
    if (tid < 16) b2i[tid] = make_float4(b2s[tid], b2x[tid], b2y[tid], 0.0f);
    for (int i = tid; i < 1176; i += TPB) h1p[i] = 0.0f;
    __syncthreads();

    float gxr[4][2][2], gyr[4][2][2];
    #pragma unroll
    for (int it = 0; it < 4; ++it) {
        int idx = tid + it * TPB;
        if (idx < 864) {
            int c = idx / 144, p = idx % 144;
            int py = p / 12, px = p % 12;
            float a[6][6];
            #pragma unroll
            for (int r = 0; r < 6; ++r) {
                const float2* rp = (const float2*)&xs_p[(2 * py + r) * 28 + 2 * px];
                float2 v0 = rp[0], v1 = rp[1], v2 = rp[2];
                a[r][0] = v0.x; a[r][1] = v0.y; a[r][2] = v1.x;
                a[r][3] = v1.y; a[r][4] = v2.x; a[r][5] = v2.y;
            }
            float4 bb = b1i[c];
            float s[2][2], agx[2][2], agy[2][2];
            #pragma unroll
            for (int dy = 0; dy < 2; ++dy)
                #pragma unroll
                for (int dx = 0; dx < 2; ++dx) { s[dy][dx] = bb.x; agx[dy][dx] = bb.y; agy[dy][dx] = bb.z; }
            #pragma unroll
            for (int ky = 0; ky < 5; ++ky)
                #pragma unroll
                for (int kx = 0; kx < 5; ++kx) {
                    float4 w = w1i[c * 25 + ky * 5 + kx];
                    #pragma unroll
                    for (int dy = 0; dy < 2; ++dy)
                        #pragma unroll
                        for (int dx = 0; dx < 2; ++dx) {
                            float v = a[ky + dy][kx + dx];
                            s[dy][dx]   = fmaf(v, w.x, s[dy][dx]);
                            agx[dy][dx] = fmaf(v, w.y, agx[dy][dx]);
                            agy[dy][dx] = fmaf(v, w.z, agy[dy][dx]);
                        }
                }
            float* sm = &smap1[c * 576 + (2 * py) * 24 + 2 * px];
            sm[0] = s[0][0]; sm[1] = s[0][1]; sm[24] = s[1][0]; sm[25] = s[1][1];
            #pragma unroll
            for (int dy = 0; dy < 2; ++dy)
                #pragma unroll
                for (int dx = 0; dx < 2; ++dx) { gxr[it][dy][dx] = agx[dy][dx]; gyr[it][dy][dx] = agy[dy][dx]; }
        }
    }
    __syncthreads();

    #pragma unroll
    for (int it = 0; it < 4; ++it) {
        int idx = tid + it * TPB;
        if (idx < 864) {
            int c = idx / 144, p = idx % 144;
            int py = p / 12, px = p % 12;
            const float* smc = &smap1[c * 576];
            float mx = 0.0f;
            #pragma unroll
            for (int dy = 0; dy < 2; ++dy)
                #pragma unroll
                for (int dx = 0; dx < 2; ++dx)
                    mx = fmaxf(mx, bilin_zero_s(smc, 24, 24, gxr[it][dy][dx], gyr[it][dy][dx]));
            h1p[c * 196 + (py + 1) * 14 + (px + 1)] = mx;
        }
    }
    __syncthreads();

    float gxr2[2][2][2], gyr2[2][2][2];
    #pragma unroll
    for (int it = 0; it < 2; ++it) {
        int idx = tid + it * TPB;
        if (idx < 400) {
            int c = idx / 25, p = idx % 25;
            int py = p / 5, px = p % 5;
            float4 bb = b2i[c];
            float s[2][2], agx[2][2], agy[2][2];
            #pragma unroll
            for (int dy = 0; dy < 2; ++dy)
                #pragma unroll
                for (int dx = 0; dx < 2; ++dx) { s[dy][dx] = bb.x; agx[dy][dx] = bb.y; agy[dy][dx] = bb.z; }
            for (int i = 0; i < 6; ++i) {
                float a[6][6];
                #pragma unroll
                for (int r = 0; r < 6; ++r) {
                    const float2* rp = (const float2*)&h1p[i * 196 + (2 * py + r) * 14 + 2 * px];
                    float2 v0 = rp[0], v1 = rp[1], v2 = rp[2];
                    a[r][0] = v0.x; a[r][1] = v0.y; a[r][2] = v1.x;
                    a[r][3] = v1.y; a[r][4] = v2.x; a[r][5] = v2.y;
                }
                const float4* wc = &w2i[c * 150 + i * 25];
                #pragma unroll
                for (int ky = 0; ky < 5; ++ky)
                    #pragma unroll
                    for (int kx = 0; kx < 5; ++kx) {
                        float4 w = wc[ky * 5 + kx];
                        #pragma unroll
                        for (int dy = 0; dy < 2; ++dy)
                            #pragma unroll
                            for (int dx = 0; dx < 2; ++dx) {
                                float v = a[ky + dy][kx + dx];
                                s[dy][dx]   = fmaf(v, w.x, s[dy][dx]);
                                agx[dy][dx] = fmaf(v, w.y, agx[dy][dx]);
                                agy[dy][dx] = fmaf(v, w.z, agy[dy][dx]);
                            }
                    }
            }
            float* sm = &smap2[c * 100 + (2 * py) * 10 + 2 * px];
            sm[0] = s[0][0]; sm[1] = s[0][1]; sm[10] = s[1][0]; sm[11] = s[1][1];
            #pragma unroll
            for (int dy = 0; dy < 2; ++dy)
                #pragma unroll
                for (int dx = 0; dx < 2; ++dx) { gxr2[it][dy][dx] = agx[dy][dx]; gyr2[it][dy][dx] = agy[dy][dx]; }
        }
    }
    __syncthreads();

    #pragma unroll
    for (int it = 0; it < 2; ++it) {
        int idx = tid + it * TPB;
        if (idx < 400) {
            int c = idx / 25, p = idx % 25;
            int py = p / 5, px = p % 5;
            const float* smc = &smap2[c * 100];
            float mx = 0.0f;
            #pragma unroll
            for (int dy = 0; dy < 2; ++dy)
                #pragma unroll
                for (int dx = 0; dx < 2; ++dx)
                    mx = fmaxf(mx, bilin_zero_s(smc, 10, 10, gxr2[it][dy][dx], gyr2[it][dy][dx]));
            h2[c * 25 + py * 5 + px] = mx;
        }
    }
    __syncthreads();

    if (tid < 240) {
        int o = tid >> 1, h = tid & 1;
        const float4* wrow = (const float4*)(wf1 + o * 400 + h * 200);
        const float4* hh   = (const float4*)&h2[h * 200];
        float acc = 0.0f;
        for (int k = 0; k < 50; ++k) {
            float4 w = wrow[k]; float4 v = hh[k];
            acc = fmaf(w.x, v.x, acc); acc = fmaf(w.y, v.y, acc);
            acc = fmaf(w.z, v.z, acc); acc = fmaf(w.w, v.w, acc);
        }
        acc += __shfl_xor(acc, 1);
        if (h == 0) f1[o] = fmaxf(acc + bf1[o], 0.0f);
    }
    __syncthreads();

    if (tid < 84) {
        const float4* wrow = (const float4*)(wf2 + tid * 120);
        const float4* hh   = (const float4*)f1;
        float acc = bf2[tid];
        for (int k = 0; k < 30; ++k) {
            float4 w = wrow[k]; float4 v = hh[k];
            acc = fmaf(w.x, v.x, acc); acc = fmaf(w.y, v.y, acc);
            acc = fmaf(w.z, v.z, acc); acc = fmaf(w.w, v.w, acc);
        }
        f2[tid] = fmaxf(acc, 0.0f);
    }
    __syncthreads();

    if (tid < 10) {
        const float4* wrow = (const float4*)(wf3 + tid * 84);
        const float4* hh   = (const float4*)f2;
        float acc = bf3[tid];
        for (int k = 0; k < 21; ++k) {
            float4 w = wrow[k]; float4 v = hh[k];
            acc = fmaf(w.x, v.x, acc); acc = fmaf(w.y, v.y, acc);
            acc = fmaf(w.z, v.z, acc); acc = fmaf(w.w, v.w, acc);
        }
        f3[tid] = acc;
    }
    __syncthreads();

    if (tid < 10) {
        float m = f3[0];
        #pragma unroll
        for (int j = 1; j < 10; ++j) m = fmaxf(m, f3[j]);
        float ssum = 0.0f;
        #pragma unroll
        for (int j = 0; j < 10; ++j) ssum += expf(f3[j] - m);
        out[b * 10 + tid] = expf(f3[tid] - m) / ssum;
    }
}

extern "C" void kernel_launch(void* const* d_in, const int* in_sizes, int n_in,
                              void* d_out, int out_size, void* d_ws, size_t ws_size,
                              hipStream_t stream) {
    const float* x   = (const float*)d_in[0];
    const float* w1s = (const float*)d_in[1];
    const float* b1s = (const float*)d_in[2];
    const float* w1x = (const float*)d_in[3];
    const float* b1x = (const float*)d_in[4];
    const float* w1y = (const float*)d_in[5];
    const float* b1y = (const float*)d_in[6];
    const float* w2s = (const float*)d_in[7];
    const float* b2s = (const float*)d_in[8];
    const float* w2x = (const float*)d_in[9];
    const float* b2x = (const float*)d_in[10];
    const float* w2y = (const float*)d_in[11];
    const float* b2y = (const float*)d_in[12];
    const float* wf1 = (const float*)d_in[13];
    const float* bf1 = (const float*)d_in[14];
    const float* wf2 = (const float*)d_in[15];
    const float* bf2 = (const float*)d_in[16];
    const float* wf3 = (const float*)d_in[17];
    const float* bf3 = (const float*)d_in[18];
    float* out = (float*)d_out;

    if (ws_size >= REQ_WS_BYTES) {
        float* wsf = (float*)d_ws;
        lenet_prep<<<64, TPB, 0, stream>>>(w1s, w1x, w1y, w2s, w2x, w2y,
                                           wf1, wf2, wf3, wsf);
        lenetA<<<8192, TPBA, 0, stream>>>(x, wsf, b1s, b1x, b1y, wsf + OFF_H1);
        lenetB<<<4096, TPB, 0, stream>>>(wsf + OFF_H1, wsf, b2s, b2x, b2y, wsf + OFF_H2);
        lenetC<<<512, TPBC, 0, stream>>>(wsf + OFF_H2, wsf, bf1, bf2, bf3, out);
    } else {
        lenet_off_fused<<<8192, TPB, 0, stream>>>(
            x, w1s, b1s, w1x, b1x, w1y, b1y,
            w2s, b2s, w2x, b2x, w2y, b2y,
            wf1, bf1, wf2, bf2, wf3, bf3, out);
    }
}

// Round 10
// 308.955 us; speedup vs baseline: 1.0675x; 1.0675x over previous
//
#include <hip/hip_runtime.h>
#include <math.h>

#define TPB 256
#define TPBA 448
#define TPBC 512

#define XS_S   34
#define SM1_S  26
#define SM1_C  624
#define H1P_R  18
#define H1P_C  252
#define H1P_I  1512

typedef float v2f __attribute__((ext_vector_type(2)));

// acc(lo,hi) += broadcast(ap.lo) * w(lo,hi)   (still used by kernel A)
__device__ __forceinline__ void pk_lo(v2f& acc, v2f ap, v2f w) {
    asm("v_pk_fma_f32 %0, %1, %2, %0 op_sel:[0,0,0] op_sel_hi:[0,1,1]"
        : "+v"(acc) : "v"(ap), "v"(w));
}
__device__ __forceinline__ void pk_hi(v2f& acc, v2f ap, v2f w) {
    asm("v_pk_fma_f32 %0, %1, %2, %0 op_sel:[1,0,0] op_sel_hi:[1,1,1]"
        : "+v"(acc) : "v"(ap), "v"(w));
}

// ---------------- workspace layout (floats) ----------------
#define OFF_WA_SX 0
#define OFF_WA_YY 300
#define OFF_WB_SX 464
#define OFF_WB_YY 5264
#define OFF_WF1T  7664
#define OFF_WF2T  55664
#define OFF_WF3T  65744
#define OFF_H1    66592
#define OFF_H2    7144480
#define WS_FLOATS 10421280ull
#define REQ_WS_BYTES (WS_FLOATS * 4ull)

__device__ __forceinline__ float bilin_zero_s(const float* __restrict__ img, int N, int S,
                                              float gx, float gy) {
    float fx = (gx + 1.0f) * (0.5f * (float)N) - 0.5f;
    float fy = (gy + 1.0f) * (0.5f * (float)N) - 0.5f;
    float x0 = floorf(fx), y0 = floorf(fy);
    float wx1 = fx - x0, wy1 = fy - y0;
    float wx0 = 1.0f - wx1, wy0 = 1.0f - wy1;
    float x1 = x0 + 1.0f, y1 = y0 + 1.0f;
    float Nm1 = (float)(N - 1);
    int xi0 = (int)fminf(fmaxf(x0, 0.0f), Nm1);
    int yi0 = (int)fminf(fmaxf(y0, 0.0f), Nm1);
    int xi1 = (int)fminf(fmaxf(x1, 0.0f), Nm1);
    int yi1 = (int)fminf(fmaxf(y1, 0.0f), Nm1);
    bool vx0 = (x0 >= 0.0f) && (x0 < (float)N);
    bool vx1 = (x1 >= 0.0f) && (x1 < (float)N);
    bool vy0 = (y0 >= 0.0f) && (y0 < (float)N);
    bool vy1 = (y1 >= 0.0f) && (y1 < (float)N);
    float v00 = (vy0 && vx0) ? img[yi0 * S + xi0] : 0.0f;
    float v01 = (vy0 && vx1) ? img[yi0 * S + xi1] : 0.0f;
    float v10 = (vy1 && vx0) ? img[yi1 * S + xi0] : 0.0f;
    float v11 = (vy1 && vx1) ? img[yi1 * S + xi1] : 0.0f;
    return v00 * wy0 * wx0 + v01 * wy0 * wx1 + v10 * wy1 * wx0 + v11 * wy1 * wx1;
}

// ================= prep =================
__global__ __launch_bounds__(TPB) void lenet_prep(
    const float* __restrict__ w1s, const float* __restrict__ w1x, const float* __restrict__ w1y,
    const float* __restrict__ w2s, const float* __restrict__ w2x, const float* __restrict__ w2y,
    const float* __restrict__ wf1, const float* __restrict__ wf2, const float* __restrict__ wf3,
    float* __restrict__ wsf)
{
    int g = blockIdx.x * TPB + threadIdx.x;
    int stride = gridDim.x * TPB;
    for (int i = g; i < 75; i += stride) {
        int cp = i / 25, t = i % 25;
        int cA = (2 * cp) * 25 + t, cB = (2 * cp + 1) * 25 + t;
        float* p = wsf + OFF_WA_SX + i * 4;
        p[0] = w1s[cA]; p[1] = w1x[cA]; p[2] = w1s[cB]; p[3] = w1x[cB];
        wsf[OFF_WA_YY + i * 2 + 0] = w1y[cA];
        wsf[OFF_WA_YY + i * 2 + 1] = w1y[cB];
    }
    for (int e = g; e < 1200; e += stride) {
        int cp = e / 150, rem = e % 150;
        int iA = cp * 150 + rem, iB = (cp + 8) * 150 + rem;
        float* pp = wsf + OFF_WB_SX + e * 4;
        pp[0] = w2s[iA]; pp[1] = w2s[iB]; pp[2] = w2x[iA]; pp[3] = w2x[iB];
        wsf[OFF_WB_YY + e * 2 + 0] = w2y[iA];
        wsf[OFF_WB_YY + e * 2 + 1] = w2y[iB];
    }
    for (int i = g; i < 48000; i += stride) { int k = i / 120, o = i % 120; wsf[OFF_WF1T + i] = wf1[o * 400 + k]; }
    for (int i = g; i < 10080; i += stride) { int k = i / 84,  o = i % 84;  wsf[OFF_WF2T + i] = wf2[o * 120 + k]; }
    for (int i = g; i < 840;   i += stride) { int k = i / 10,  o = i % 10;  wsf[OFF_WF3T + i] = wf3[o * 84 + k]; }
}

// ================= kernel A (unchanged from R8 best) =================
__global__ __launch_bounds__(TPBA) void lenetA(
    const float* __restrict__ x, const float* __restrict__ wsf,
    const float* __restrict__ b1s, const float* __restrict__ b1x, const float* __restrict__ b1y,
    float* __restrict__ h1)
{
    __shared__ __align__(16) float xs_p[28 * XS_S];
    __shared__ float4 w1i[150];
    __shared__ float4 b1w[3];
    __shared__ v2f    b1yw[3];
    __shared__ __align__(16) float smap1[6 * SM1_C];

    const int tid = threadIdx.x, b = blockIdx.x;
    const float* xp = x + b * 676;
    for (int i = tid; i < 28 * XS_S; i += TPBA) {
        int r = i / XS_S, c = i % XS_S;
        float v = 0.0f;
        if (c < 28 && r >= 1 && r <= 26 && c >= 1 && c <= 26) v = xp[(r - 1) * 26 + (c - 1)];
        xs_p[i] = v;
    }
    if (tid < 150) w1i[tid] = ((const float4*)(wsf + OFF_WA_SX))[tid];
    if (tid < 3) {
        b1w[tid]  = make_float4(b1s[2 * tid], b1x[2 * tid], b1s[2 * tid + 1], b1x[2 * tid + 1]);
        b1yw[tid] = (v2f){b1y[2 * tid], b1y[2 * tid + 1]};
    }
    __syncthreads();

    const v2f* wyy = (const v2f*)(wsf + OFF_WA_YY);

    const int cp = tid / 144, p = tid % 144;
    const int py = p / 12, px = p % 12;
    const bool act = (tid < 432);

    float gxa[2][2][2], gya[2][2][2];
    if (act) {
        v2f aw[6][3];
        #pragma unroll
        for (int r = 0; r < 6; ++r) {
            const v2f* rp = (const v2f*)&xs_p[(2 * py + r) * XS_S + 2 * px];
            aw[r][0] = rp[0]; aw[r][1] = rp[1]; aw[r][2] = rp[2];
        }
        int c0 = 2 * cp, c1 = 2 * cp + 1;
        v2f a0[2][2], a1[2][2], ay[2][2];
        {
            float4 bb = b1w[cp];
            v2f i0 = {bb.x, bb.y};
            v2f i1 = {bb.z, bb.w};
            v2f iy = b1yw[cp];
            #pragma unroll
            for (int dy = 0; dy < 2; ++dy)
                #pragma unroll
                for (int dx = 0; dx < 2; ++dx) { a0[dy][dx] = i0; a1[dy][dx] = i1; ay[dy][dx] = iy; }
        }
        const float4* wp  = &w1i[cp * 25];
        const v2f*    wyp = wyy + cp * 25;
        #pragma unroll
        for (int ky = 0; ky < 5; ++ky)
            #pragma unroll
            for (int kx = 0; kx < 5; ++kx) {
                float4 w4 = wp[ky * 5 + kx];
                v2f wA = {w4.x, w4.y};
                v2f wB = {w4.z, w4.w};
                v2f wy = wyp[ky * 5 + kx];
                #pragma unroll
                for (int dy = 0; dy < 2; ++dy)
                    #pragma unroll
                    for (int dx = 0; dx < 2; ++dx) {
                        int cc = kx + dx;
                        v2f ap = aw[ky + dy][cc >> 1];
                        if ((cc & 1) == 0) {
                            pk_lo(a0[dy][dx], ap, wA);
                            pk_lo(a1[dy][dx], ap, wB);
                            pk_lo(ay[dy][dx], ap, wy);
                        } else {
                            pk_hi(a0[dy][dx], ap, wA);
                            pk_hi(a1[dy][dx], ap, wB);
                            pk_hi(ay[dy][dx], ap, wy);
                        }
                    }
            }
        {
            int base0 = (2 * py) * SM1_S + 2 * px;
            int base1 = base0 + SM1_S;
            *(v2f*)&smap1[c0 * SM1_C + base0] = (v2f){a0[0][0].x, a0[0][1].x};
            *(v2f*)&smap1[c0 * SM1_C + base1] = (v2f){a0[1][0].x, a0[1][1].x};
            *(v2f*)&smap1[c1 * SM1_C + base0] = (v2f){a1[0][0].x, a1[0][1].x};
            *(v2f*)&smap1[c1 * SM1_C + base1] = (v2f){a1[1][0].x, a1[1][1].x};
        }
        #pragma unroll
        for (int dy = 0; dy < 2; ++dy)
            #pragma unroll
            for (int dx = 0; dx < 2; ++dx) {
                gxa[0][dy][dx] = a0[dy][dx].y;  gya[0][dy][dx] = ay[dy][dx].x;
                gxa[1][dy][dx] = a1[dy][dx].y;  gya[1][dy][dx] = ay[dy][dx].y;
            }
    }
    __syncthreads();

    if (act) {
        #pragma unroll
        for (int ch = 0; ch < 2; ++ch) {
            int c = 2 * cp + ch;
            const float* smc = &smap1[c * SM1_C];
            float mx = 0.0f;
            #pragma unroll
            for (int dy = 0; dy < 2; ++dy)
                #pragma unroll
                for (int dx = 0; dx < 2; ++dx)
                    mx = fmaxf(mx, bilin_zero_s(smc, 24, SM1_S, gxa[ch][dy][dx], gya[ch][dy][dx]));
            h1[(size_t)b * 864 + c * 144 + p] = mx;
        }
    }
}

// ================= kernel B: wave-sync, PLAIN fmaf accumulation (pk-asm removed) =================
__global__ __launch_bounds__(TPB, 6) void lenetB(
    const float* __restrict__ h1, const float* __restrict__ wsf,
    const float* __restrict__ b2s, const float* __restrict__ b2x, const float* __restrict__ b2y,
    float* __restrict__ h2)
{
    __shared__ __align__(16) float h1p[2 * H1P_I];
    __shared__ __align__(16) float wsm[4][2][2][100];

    const int tid = threadIdx.x, b = blockIdx.x;

    for (int i = tid; i < 2 * H1P_I; i += TPB) {
        int im = i / H1P_I;
        int k = i - im * H1P_I;
        int ch = k / H1P_C, p2 = k % H1P_C;
        int r = p2 / H1P_R, c = p2 % H1P_R;
        float v = 0.0f;
        if (c < 14 && r >= 1 && r <= 12 && c >= 1 && c <= 12)
            v = h1[(size_t)(2 * b + im) * 864 + ch * 144 + (r - 1) * 12 + (c - 1)];
        h1p[i] = v;
    }
    __syncthreads();  // the only block barrier

    const int lane = tid & 63;
    const int wvu  = __builtin_amdgcn_readfirstlane(tid >> 6);
    const int img  = lane >> 5;
    const int p    = lane & 31;
    const bool act = (p < 25);
    const int py = p / 5, px = p % 5;

    const float4* wsx = (const float4*)(wsf + OFF_WB_SX);
    const v2f*    wyy = (const v2f*)   (wsf + OFF_WB_YY);
    float* smw = &wsm[wvu][img][0][0];
    const float* h1pi = &h1p[img * H1P_I];

    #pragma unroll
    for (int rep = 0; rep < 2; ++rep) {
        const int cp = wvu + 4 * rep;
        if (rep) {
            asm volatile("s_waitcnt lgkmcnt(0)" ::: "memory");
            __builtin_amdgcn_sched_barrier(0);
        }
        // scalar accumulators: [dy][dx] for each of (s,x,y) x (slot0=cp, slot1=cp+8)
        float s0[2][2], s1[2][2], x0[2][2], x1[2][2], y0[2][2], y1[2][2];
        if (act) {
            {
                float is0 = b2s[cp], is1 = b2s[cp + 8];
                float ix0 = b2x[cp], ix1 = b2x[cp + 8];
                float iy0 = b2y[cp], iy1 = b2y[cp + 8];
                #pragma unroll
                for (int dy = 0; dy < 2; ++dy)
                    #pragma unroll
                    for (int dx = 0; dx < 2; ++dx) {
                        s0[dy][dx] = is0; s1[dy][dx] = is1;
                        x0[dy][dx] = ix0; x1[dy][dx] = ix1;
                        y0[dy][dx] = iy0; y1[dy][dx] = iy1;
                    }
            }
            #pragma unroll
            for (int i = 0; i < 6; ++i) {
                v2f aw[6][3];
                #pragma unroll
                for (int r = 0; r < 6; ++r) {
                    const v2f* rp = (const v2f*)&h1pi[i * H1P_C + (2 * py + r) * H1P_R + 2 * px];
                    aw[r][0] = rp[0]; aw[r][1] = rp[1]; aw[r][2] = rp[2];
                }
                const float4* wt  = wsx + (cp * 6 + i) * 25;
                const v2f*    wyt = wyy + (cp * 6 + i) * 25;
                #pragma unroll
                for (int ky = 0; ky < 5; ++ky)
                    #pragma unroll
                    for (int kx = 0; kx < 5; ++kx) {
                        float4 w4 = wt[ky * 5 + kx];   // (s_cp, s_cp8, x_cp, x_cp8)
                        v2f    wy = wyt[ky * 5 + kx];  // (y_cp, y_cp8)
                        #pragma unroll
                        for (int dy = 0; dy < 2; ++dy)
                            #pragma unroll
                            for (int dx = 0; dx < 2; ++dx) {
                                int cc = kx + dx;
                                v2f ap = aw[ky + dy][cc >> 1];
                                float av = (cc & 1) ? ap.y : ap.x;
                                s0[dy][dx] = fmaf(av, w4.x, s0[dy][dx]);
                                s1[dy][dx] = fmaf(av, w4.y, s1[dy][dx]);
                                x0[dy][dx] = fmaf(av, w4.z, x0[dy][dx]);
                                x1[dy][dx] = fmaf(av, w4.w, x1[dy][dx]);
                                y0[dy][dx] = fmaf(av, wy.x, y0[dy][dx]);
                                y1[dy][dx] = fmaf(av, wy.y, y1[dy][dx]);
                            }
                    }
            }
            {
                int base0 = (2 * py) * 10 + 2 * px;
                int base1 = base0 + 10;
                *(v2f*)&smw[base0]       = (v2f){s0[0][0], s0[0][1]};
                *(v2f*)&smw[base1]       = (v2f){s0[1][0], s0[1][1]};
                *(v2f*)&smw[100 + base0] = (v2f){s1[0][0], s1[0][1]};
                *(v2f*)&smw[100 + base1] = (v2f){s1[1][0], s1[1][1]};
            }
        }
        asm volatile("s_waitcnt lgkmcnt(0)" ::: "memory");
        __builtin_amdgcn_sched_barrier(0);
        if (act) {
            #pragma unroll
            for (int slot = 0; slot < 2; ++slot) {
                int c = cp + slot * 8;
                const float* smc = &smw[slot * 100];
                float mx = 0.0f;
                #pragma unroll
                for (int dy = 0; dy < 2; ++dy)
                    #pragma unroll
                    for (int dx = 0; dx < 2; ++dx) {
                        float gx = slot ? x1[dy][dx] : x0[dy][dx];
                        float gy = slot ? y1[dy][dx] : y0[dy][dx];
                        mx = fmaxf(mx, bilin_zero_s(smc, 10, 10, gx, gy));
                    }
                h2[(size_t)(2 * b + img) * 400 + c * 25 + p] = mx;
            }
        }
    }
}

// ================= kernel C (unchanged) =================
__global__ __launch_bounds__(TPBC) void lenetC(
    const float* __restrict__ h2, const float* __restrict__ wsf,
    const float* __restrict__ bf1, const float* __restrict__ bf2, const float* __restrict__ bf3,
    float* __restrict__ out)
{
    __shared__ __align__(16) float h2s[8][2][400];
    __shared__ float f1s[8][2][120];
    __shared__ float f2s[8][2][84];
    __shared__ float f3s[8][2][10];

    const int tid = threadIdx.x;
    const int w = tid >> 6, lane = tid & 63;
    const int img0 = blockIdx.x * 16 + w * 2;

    for (int j = 0; j < 2; ++j) {
        float4*       dst = (float4*)&h2s[w][j][0];
        const float4* src = (const float4*)&h2[(img0 + j) * 400];
        for (int k = lane; k < 100; k += 64) dst[k] = src[k];
    }
    __syncthreads();

    {
        const float* wf1T = wsf + OFF_WF1T;
        float acc1[2] = {0, 0}, acc2[2] = {0, 0};
        for (int k = 0; k < 400; ++k) {
            float wa = wf1T[k * 120 + lane];
            float wb = (lane < 56) ? wf1T[k * 120 + 64 + lane] : 0.0f;
            #pragma unroll
            for (int j = 0; j < 2; ++j) {
                float hv = h2s[w][j][k];
                acc1[j] = fmaf(hv, wa, acc1[j]);
                acc2[j] = fmaf(hv, wb, acc2[j]);
            }
        }
        float bb1 = bf1[lane];
        float bb2 = (lane < 56) ? bf1[64 + lane] : 0.0f;
        #pragma unroll
        for (int j = 0; j < 2; ++j) {
            f1s[w][j][lane] = fmaxf(acc1[j] + bb1, 0.0f);
            if (lane < 56) f1s[w][j][64 + lane] = fmaxf(acc2[j] + bb2, 0.0f);
        }
    }
    __syncthreads();

    {
        const float* wf2T = wsf + OFF_WF2T;
        float acc1[2], acc2[2];
        float bb1 = bf2[lane];
        float bb2 = (lane < 20) ? bf2[64 + lane] : 0.0f;
        #pragma unroll
        for (int j = 0; j < 2; ++j) { acc1[j] = bb1; acc2[j] = bb2; }
        for (int k = 0; k < 120; ++k) {
            float wa = wf2T[k * 84 + lane];
            float wb = (lane < 20) ? wf2T[k * 84 + 64 + lane] : 0.0f;
            #pragma unroll
            for (int j = 0; j < 2; ++j) {
                float hv = f1s[w][j][k];
                acc1[j] = fmaf(hv, wa, acc1[j]);
                acc2[j] = fmaf(hv, wb, acc2[j]);
            }
        }
        #pragma unroll
        for (int j = 0; j < 2; ++j) {
            f2s[w][j][lane] = fmaxf(acc1[j], 0.0f);
            if (lane < 20) f2s[w][j][64 + lane] = fmaxf(acc2[j], 0.0f);
        }
    }
    __syncthreads();

    if (lane < 10) {
        const float* wf3T = wsf + OFF_WF3T;
        float acc[2];
        float bb = bf3[lane];
        #pragma unroll
        for (int j = 0; j < 2; ++j) acc[j] = bb;
        for (int k = 0; k < 84; ++k) {
            float wv = wf3T[k * 10 + lane];
            #pragma unroll
            for (int j = 0; j < 2; ++j) acc[j] = fmaf(f2s[w][j][k], wv, acc[j]);
        }
        #pragma unroll
        for (int j = 0; j < 2; ++j) f3s[w][j][lane] = acc[j];
    }
    __syncthreads();

    if (lane < 20) {
        int j = lane / 10, c = lane % 10;
        float m = f3s[w][j][0];
        #pragma unroll
        for (int q = 1; q < 10; ++q) m = fmaxf(m, f3s[w][j][q]);
        float ssum = 0.0f;
        #pragma unroll
        for (int q = 0; q < 10; ++q) ssum += expf(f3s[w][j][q] - m);
        out[(img0 + j) * 10 + c] = expf(f3s[w][j][c] - m) / ssum;
    }
}

// ================= fallback (unchanged) =================
__global__ __launch_bounds__(TPB, 2) void lenet_off_fused(
    const float* __restrict__ x,
    const float* __restrict__ w1s, const float* __restrict__ b1s,
    const float* __restrict__ w1x, const float* __restrict__ b1x,
    const float* __restrict__ w1y, const float* __restrict__ b1y,
    const float* __restrict__ w2s, const float* __restrict__ b2s,
    const float* __restrict__ w2x, const float* __restrict__ b2x,
    const float* __restrict__ w2y, const float* __restrict__ b2y,
    const float* __restrict__ wf1, const float* __restrict__ bf1,
    const float* __restrict__ wf2, const float* __restrict__ bf2,
    const float* __restrict__ wf3, const float* __restrict__ bf3,
    float* __restrict__ out)
{
    __shared__ __align__(16) float  xs_p[784];
    __shared__ float4 w1i[150];
    __shared__ float4 b1i[6];
    __shared__ float4 w2i[2400];
    __shared__ float4 b2i[16];
    __shared__ __align__(16) float  smap1[3456];
    __shared__ __align__(16) float  h1p[1176];
    __shared__ __align__(16) float  smap2[1600];
    __shared__ __align__(16) float  h2[400];
    __shared__ __align__(16) float  f1[120];
    __shared__ __align__(16) float  f2[84];
    __shared__ float  f3[10];

    const int tid = threadIdx.x;
    const int b   = blockIdx.x;

    const float* xp = x + b * 676;
    for (int i = tid; i < 784; i += TPB) {
        int r = i / 28, c = i % 28;
        float v = 0.0f;
        if (r >= 1 && r <= 26 && c >= 1 && c <= 26) v = xp[(r - 1) * 26 + (c - 1)];
        xs_p[i] = v;
    }
    for (int i = tid; i < 150; i += TPB)
        w1i[i] = make_float4(w1s[i], w1x[i], w1y[i], 0.0f);
    if (tid < 6)  b1i[tid] = make_float4(b1s[tid], b1x[tid], b1y[tid], 0.0f);
    for (int i = tid; i < 2400; i += TPB)
        w2i[i] = make_float4(w2s[i], w2x[i], w2y[i], 0.0f);
    if (tid < 16) b2i[tid] = make_float4(b2s[tid], b2x[tid], b2y[tid], 0.0f);
    for (int i = tid; i < 1176; i += TPB) h1p[i] = 0.0f;
    __syncthreads();

    float gxr[4][2][2], gyr[4][2][2];
    #pragma unroll
    for (int it = 0; it < 4; ++it) {
        int idx = tid + it * TPB;
        if (idx < 864) {
            int c = idx / 144, p = idx % 144;
            int py = p / 12, px = p % 12;
            float a[6][6];
            #pragma unroll
            for (int r = 0; r < 6; ++r) {
                const float2* rp = (const float2*)&xs_p[(2 * py + r) * 28 + 2 * px];
                float2 v0 = rp[0], v1 = rp[1], v2 = rp[2];
                a[r][0] = v0.x; a[r][1] = v0.y; a[r][2] = v1.x;
                a[r][3] = v1.y; a[r][4] = v2.x; a[r][5] = v2.y;
            }
            float4 bb = b1i[c];
            float s[2][2], agx[2][2], agy[2][2];
            #pragma unroll
            for (int dy = 0; dy < 2; ++dy)
                #pragma unroll
                for (int dx = 0; dx < 2; ++dx) { s[dy][dx] = bb.x; agx[dy][dx] = bb.y; agy[dy][dx] = bb.z; }
            #pragma unroll
            for (int ky = 0; ky < 5; ++ky)
                #pragma unroll
                for (int kx = 0; kx < 5; ++kx) {
                    float4 w = w1i[c * 25 + ky * 5 + kx];
                    #pragma unroll
                    for (int dy = 0; dy < 2; ++dy)
                        #pragma unroll
                        for (int dx = 0; dx < 2; ++dx) {
                            float v = a[ky + dy][kx + dx];
                            s[dy][dx]   = fmaf(v, w.x, s[dy][dx]);
                            agx[dy][dx] = fmaf(v, w.y, agx[dy][dx]);
                            agy[dy][dx] = fmaf(v, w.z, agy[dy][dx]);
                        }
                }
            float* sm = &smap1[c * 576 + (2 * py) * 24 + 2 * px];
            sm[0] = s[0][0]; sm[1] = s[0][1]; sm[24] = s[1][0]; sm[25] = s[1][1];
            #pragma unroll
            for (int dy = 0; dy < 2; ++dy)
                #pragma unroll
                for (int dx = 0; dx < 2; ++dx) { gxr[it][dy][dx] = agx[dy][dx]; gyr[it][dy][dx] = agy[dy][dx]; }
        }
    }
    __syncthreads();

    #pragma unroll
    for (int it = 0; it < 4; ++it) {
        int idx = tid + it * TPB;
        if (idx < 864) {
            int c = idx / 144, p = idx % 144;
            int py = p / 12, px = p % 12;
            const float* smc = &smap1[c * 576];
            float mx = 0.0f;
            #pragma unroll
            for (int dy = 0; dy < 2; ++dy)
                #pragma unroll
                for (int dx = 0; dx < 2; ++dx)
                    mx = fmaxf(mx, bilin_zero_s(smc, 24, 24, gxr[it][dy][dx], gyr[it][dy][dx]));
            h1p[c * 196 + (py + 1) * 14 + (px + 1)] = mx;
        }
    }
    __syncthreads();

    float gxr2[2][2][2], gyr2[2][2][2];
    #pragma unroll
    for (int it = 0; it < 2; ++it) {
        int idx = tid + it * TPB;
        if (idx < 400) {
            int c = idx / 25, p = idx % 25;
            int py = p / 5, px = p % 5;
            float4 bb = b2i[c];
            float s[2][2], agx[2][2], agy[2][2];
            #pragma unroll
            for (int dy = 0; dy < 2; ++dy)
                #pragma unroll
                for (int dx = 0; dx < 2; ++dx) { s[dy][dx] = bb.x; agx[dy][dx] = bb.y; agy[dy][dx] = bb.z; }
            for (int i = 0; i < 6; ++i) {
                float a[6][6];
                #pragma unroll
                for (int r = 0; r < 6; ++r) {
                    const float2* rp = (const float2*)&h1p[i * 196 + (2 * py + r) * 14 + 2 * px];
                    float2 v0 = rp[0], v1 = rp[1], v2 = rp[2];
                    a[r][0] = v0.x; a[r][1] = v0.y; a[r][2] = v1.x;
                    a[r][3] = v1.y; a[r][4] = v2.x; a[r][5] = v2.y;
                }
                const float4* wc = &w2i[c * 150 + i * 25];
                #pragma unroll
                for (int ky = 0; ky < 5; ++ky)
                    #pragma unroll
                    for (int kx = 0; kx < 5; ++kx) {
                        float4 w = wc[ky * 5 + kx];
                        #pragma unroll
                        for (int dy = 0; dy < 2; ++dy)
                            #pragma unroll
                            for (int dx = 0; dx < 2; ++dx) {
                                float v = a[ky + dy][kx + dx];
                                s[dy][dx]   = fmaf(v, w.x, s[dy][dx]);
                                agx[dy][dx] = fmaf(v, w.y, agx[dy][dx]);
                                agy[dy][dx] = fmaf(v, w.z, agy[dy][dx]);
                            }
                    }
            }
            float* sm = &smap2[c * 100 + (2 * py) * 10 + 2 * px];
            sm[0] = s[0][0]; sm[1] = s[0][1]; sm[10] = s[1][0]; sm[11] = s[1][1];
            #pragma unroll
            for (int dy = 0; dy < 2; ++dy)
                #pragma unroll
                for (int dx = 0; dx < 2; ++dx) { gxr2[it][dy][dx] = agx[dy][dx]; gyr2[it][dy][dx] = agy[dy][dx]; }
        }
    }
    __syncthreads();

    #pragma unroll
    for (int it = 0; it < 2; ++it) {
        int idx = tid + it * TPB;
        if (idx < 400) {
            int c = idx / 25, p = idx % 25;
            int py = p / 5, px = p % 5;
            const float* smc = &smap2[c * 100];
            float mx = 0.0f;
            #pragma unroll
            for (int dy = 0; dy < 2; ++dy)
                #pragma unroll
                for (int dx = 0; dx < 2; ++dx)
                    mx = fmaxf(mx, bilin_zero_s(smc, 10, 10, gxr2[it][dy][dx], gyr2[it][dy][dx]));
            h2[c * 25 + py * 5 + px] = mx;
        }
    }
    __syncthreads();

    if (tid < 240) {
        int o = tid >> 1, h = tid & 1;
        const float4* wrow = (const float4*)(wf1 + o * 400 + h * 200);
        const float4* hh   = (const float4*)&h2[h * 200];
        float acc = 0.0f;
        for (int k = 0; k < 50; ++k) {
            float4 w = wrow[k]; float4 v = hh[k];
            acc = fmaf(w.x, v.x, acc); acc = fmaf(w.y, v.y, acc);
            acc = fmaf(w.z, v.z, acc); acc = fmaf(w.w, v.w, acc);
        }
        acc += __shfl_xor(acc, 1);
        if (h == 0) f1[o] = fmaxf(acc + bf1[o], 0.0f);
    }
    __syncthreads();

    if (tid < 84) {
        const float4* wrow = (const float4*)(wf2 + tid * 120);
        const float4* hh   = (const float4*)f1;
        float acc = bf2[tid];
        for (int k = 0; k < 30; ++k) {
            float4 w = wrow[k]; float4 v = hh[k];
            acc = fmaf(w.x, v.x, acc); acc = fmaf(w.y, v.y, acc);
            acc = fmaf(w.z, v.z, acc); acc = fmaf(w.w, v.w, acc);
        }
        f2[tid] = fmaxf(acc, 0.0f);
    }
    __syncthreads();

    if (tid < 10) {
        const float4* wrow = (const float4*)(wf3 + tid * 84);
        const float4* hh   = (const float4*)f2;
        float acc = bf3[tid];
        for (int k = 0; k < 21; ++k) {
            float4 w = wrow[k]; float4 v = hh[k];
            acc = fmaf(w.x, v.x, acc); acc = fmaf(w.y, v.y, acc);
            acc = fmaf(w.z, v.z, acc); acc = fmaf(w.w, v.w, acc);
        }
        f3[tid] = acc;
    }
    __syncthreads();

    if (tid < 10) {
        float m = f3[0];
        #pragma unroll
        for (int j = 1; j < 10; ++j) m = fmaxf(m, f3[j]);
        float ssum = 0.0f;
        #pragma unroll
        for (int j = 0; j < 10; ++j) ssum += expf(f3[j] - m);
        out[b * 10 + tid] = expf(f3[tid] - m) / ssum;
    }
}

extern "C" void kernel_launch(void* const* d_in, const int* in_sizes, int n_in,
                              void* d_out, int out_size, void* d_ws, size_t ws_size,
                              hipStream_t stream) {
    const float* x   = (const float*)d_in[0];
    const float* w1s = (const float*)d_in[1];
    const float* b1s = (const float*)d_in[2];
    const float* w1x = (const float*)d_in[3];
    const float* b1x = (const float*)d_in[4];
    const float* w1y = (const float*)d_in[5];
    const float* b1y = (const float*)d_in[6];
    const float* w2s = (const float*)d_in[7];
    const float* b2s = (const float*)d_in[8];
    const float* w2x = (const float*)d_in[9];
    const float* b2x = (const float*)d_in[10];
    const float* w2y = (const float*)d_in[11];
    const float* b2y = (const float*)d_in[12];
    const float* wf1 = (const float*)d_in[13];
    const float* bf1 = (const float*)d_in[14];
    const float* wf2 = (const float*)d_in[15];
    const float* bf2 = (const float*)d_in[16];
    const float* wf3 = (const float*)d_in[17];
    const float* bf3 = (const float*)d_in[18];
    float* out = (float*)d_out;

    if (ws_size >= REQ_WS_BYTES) {
        float* wsf = (float*)d_ws;
        lenet_prep<<<64, TPB, 0, stream>>>(w1s, w1x, w1y, w2s, w2x, w2y,
                                           wf1, wf2, wf3, wsf);
        lenetA<<<8192, TPBA, 0, stream>>>(x, wsf, b1s, b1x, b1y, wsf + OFF_H1);
        lenetB<<<4096, TPB, 0, stream>>>(wsf + OFF_H1, wsf, b2s, b2x, b2y, wsf + OFF_H2);
        lenetC<<<512, TPBC, 0, stream>>>(wsf + OFF_H2, wsf, bf1, bf2, bf3, out);
    } else {
        lenet_off_fused<<<8192, TPB, 0, stream>>>(
            x, w1s, b1s, w1x, b1x, w1y, b1y,
            w2s, b2s, w2x, b2x, w2y, b2y,
            wf1, bf1, wf2, bf2, wf3, bf3, out);
    }
}